// Round 6
// baseline (394.539 us; speedup 1.0000x reference)
//
#include <hip/hip_runtime.h>
#include <hip/hip_bf16.h>
#include <cstdint>
#include <cstddef>

#define D 128
#define SCAN_CHUNK 1024

typedef __attribute__((ext_vector_type(8))) __bf16 bf16v8;
typedef __attribute__((ext_vector_type(4))) float f32v4;

// Round-to-nearest-even fp32 -> bf16 (bits), packed pair.
__device__ inline unsigned int pack_bf16x2(float a, float b) {
  unsigned int ua = __float_as_uint(a);
  unsigned int ub = __float_as_uint(b);
  ua = (ua + 0x7fffu + ((ua >> 16) & 1u)) >> 16;
  ub = (ub + 0x7fffu + ((ub >> 16) & 1u)) >> 16;
  return ua | (ub << 16);
}
__device__ inline float bf_lo(unsigned int u) { return __uint_as_float(u << 16); }
__device__ inline float bf_hi(unsigned int u) { return __uint_as_float(u & 0xffff0000u); }

// ---------------------------------------------------------------------------
// Counting-sort pipeline: build dst-sorted CSR of (src, val) once per call.
// ---------------------------------------------------------------------------
__global__ __launch_bounds__(256) void hist_kernel(
    const int* __restrict__ dst, int* __restrict__ count, int E) {
  int e = blockIdx.x * 256 + threadIdx.x;
  if (e < E) atomicAdd(&count[dst[e]], 1);
}

__global__ __launch_bounds__(256) void scan_blocks(
    const int* __restrict__ count, int* __restrict__ rowptr,
    int* __restrict__ blockSums, int n) {
  __shared__ int sdata[256];
  const int tid = threadIdx.x;
  const int base = blockIdx.x * SCAN_CHUNK;
  int v[4];
#pragma unroll
  for (int k = 0; k < 4; ++k) {
    int idx = base + tid * 4 + k;
    v[k] = (idx < n) ? count[idx] : 0;
  }
  int s = v[0] + v[1] + v[2] + v[3];
  sdata[tid] = s;
  __syncthreads();
  for (int off = 1; off < 256; off <<= 1) {
    int x = (tid >= off) ? sdata[tid - off] : 0;
    __syncthreads();
    sdata[tid] += x;
    __syncthreads();
  }
  int run = sdata[tid] - s;
#pragma unroll
  for (int k = 0; k < 4; ++k) {
    int idx = base + tid * 4 + k;
    if (idx < n) rowptr[idx] = run;
    run += v[k];
  }
  if (tid == 255) blockSums[blockIdx.x] = sdata[255];
}

__global__ __launch_bounds__(256) void scan_top(int* __restrict__ bs, int nblk) {
  __shared__ int sdata[256];
  const int tid = threadIdx.x;
  int v[4];
#pragma unroll
  for (int k = 0; k < 4; ++k) {
    int idx = tid * 4 + k;
    v[k] = (idx < nblk) ? bs[idx] : 0;
  }
  int s = v[0] + v[1] + v[2] + v[3];
  sdata[tid] = s;
  __syncthreads();
  for (int off = 1; off < 256; off <<= 1) {
    int x = (tid >= off) ? sdata[tid - off] : 0;
    __syncthreads();
    sdata[tid] += x;
    __syncthreads();
  }
  int run = sdata[tid] - s;
#pragma unroll
  for (int k = 0; k < 4; ++k) {
    int idx = tid * 4 + k;
    if (idx < nblk) { int t = v[k]; bs[idx] = run; run += t; }
  }
}

__global__ __launch_bounds__(256) void add_offsets(
    int* __restrict__ rowptr, int* __restrict__ cursor,
    const int* __restrict__ bs, int n) {
  int i = blockIdx.x * 256 + threadIdx.x;
  if (i < n) {
    int v = rowptr[i] + bs[i >> 10];
    rowptr[i] = v;
    cursor[i] = v;
  }
}

__global__ __launch_bounds__(256) void scatter_edges(
    const int* __restrict__ src, const int* __restrict__ dst,
    const float* __restrict__ val, int* __restrict__ cursor,
    int2* __restrict__ sorted, int E) {
  int e = blockIdx.x * 256 + threadIdx.x;
  if (e < E) {
    int t = dst[e];
    int pos = atomicAdd(&cursor[t], 1);
    sorted[pos] = make_int2(src[e], __float_as_int(val[e]));
  }
}

// ---------------------------------------------------------------------------
// Weight cast: W (3 matrices, fp32 128x128) -> bf16, once per call.
// ---------------------------------------------------------------------------
__global__ __launch_bounds__(256) void cast_w(
    const float* __restrict__ W1, const float* __restrict__ W2,
    const float* __restrict__ W3, unsigned short* __restrict__ out) {
  const float* src[3] = {W1, W2, W3};
  int m = blockIdx.y;
  int i = blockIdx.x * 256 + threadIdx.x;
  if (i < D * D) {
    unsigned int u = __float_as_uint(src[m][i]);
    out[(size_t)m * D * D + i] =
        (unsigned short)((u + 0x7fffu + ((u >> 16) & 1u)) >> 16);
  }
}

// ---------------------------------------------------------------------------
// Dense transform Y = in @ W^T (bias/act fused into the following SpMM).
// bf16 MFMA 16x16x32, tile 128x128. Only H is LDS-staged; W (32 KB,
// L1-resident) is read as B-fragments straight from global -> LDS halved
// (34.8 KB => 4 blocks/CU).
// ---------------------------------------------------------------------------
template <int F32IN>
__global__ __launch_bounds__(256) void dense_nt(
    const void* __restrict__ in_v, const unsigned short* __restrict__ Wb,
    unsigned short* __restrict__ out, int M) {
  __shared__ __align__(16) unsigned short Hs[128 * 136];

  const int tid = threadIdx.x;
  const int w = tid >> 6;
  const int lane = tid & 63;
  const int lane15 = lane & 15;
  const int quad = lane >> 4;
  const int row0 = blockIdx.x * 128;

  if (F32IN) {
    const float4* in32 = (const float4*)in_v;  // 32 chunks of 4 floats per row
#pragma unroll
    for (int it = 0; it < 16; ++it) {
      int c = it * 256 + tid;  // 0..4095
      int r = c >> 5;
      int ck = c & 31;
      float4 g = make_float4(0.f, 0.f, 0.f, 0.f);
      if (row0 + r < M) g = in32[(size_t)(row0 + r) * 32 + ck];
      uint2 pk = make_uint2(pack_bf16x2(g.x, g.y), pack_bf16x2(g.z, g.w));
      *(uint2*)&Hs[r * 136 + ck * 4] = pk;
    }
  } else {
    const uint4* in16 = (const uint4*)in_v;  // 16 chunks per bf16 row
#pragma unroll
    for (int it = 0; it < 8; ++it) {
      int c = it * 256 + tid;
      int r = c >> 4;
      int ck = c & 15;
      uint4 g = make_uint4(0, 0, 0, 0);
      if (row0 + r < M) g = in16[(size_t)(row0 + r) * 16 + ck];
      *(uint4*)&Hs[r * 136 + ck * 8] = g;
    }
  }
  __syncthreads();

  f32v4 acc[2][8];
#pragma unroll
  for (int mt = 0; mt < 2; ++mt)
#pragma unroll
    for (int nt = 0; nt < 8; ++nt) acc[mt][nt] = (f32v4){0.f, 0.f, 0.f, 0.f};

#pragma unroll
  for (int kt = 0; kt < 4; ++kt) {
    const int ko = kt * 32 + quad * 8;
    bf16v8 a0 = *(const bf16v8*)&Hs[(w * 32 + lane15) * 136 + ko];
    bf16v8 a1 = *(const bf16v8*)&Hs[(w * 32 + 16 + lane15) * 136 + ko];
#pragma unroll
    for (int nt = 0; nt < 8; ++nt) {
      bf16v8 b = *(const bf16v8*)&Wb[(size_t)(nt * 16 + lane15) * D + ko];
      acc[0][nt] = __builtin_amdgcn_mfma_f32_16x16x32_bf16(a0, b, acc[0][nt], 0, 0, 0);
      acc[1][nt] = __builtin_amdgcn_mfma_f32_16x16x32_bf16(a1, b, acc[1][nt], 0, 0, 0);
    }
  }

#pragma unroll
  for (int mt = 0; mt < 2; ++mt) {
#pragma unroll
    for (int r = 0; r < 4; ++r) {
      int grow = row0 + w * 32 + mt * 16 + quad * 4 + r;
      if (grow < M) {
#pragma unroll
        for (int nt = 0; nt < 8; ++nt) {
          unsigned int u = __float_as_uint(acc[mt][nt][r]);
          out[(size_t)grow * D + nt * 16 + lane15] =
              (unsigned short)((u + 0x7fffu + ((u >> 16) & 1u)) >> 16);
        }
      }
    }
  }
}

// ---------------------------------------------------------------------------
// Fused SpMM, pair-gather version. One wave per row; the wave's two 32-lane
// halves each load a DIFFERENT edge's full 256B bf16 row (uint2 = 8B/lane),
// so one vmem instruction covers 2 edges. Lane l owns dims 4l..4l+3.
// Cross-half shfl_xor(32) merges the two partial sums.
// MODE 0: bias+sigmoid -> bf16.  MODE 1: bias+row-softmax -> fp32.
// ---------------------------------------------------------------------------
template <int MODE>
__global__ __launch_bounds__(256) void spmm_fused(
    const unsigned int* __restrict__ h, const int2* __restrict__ sorted,
    const int* __restrict__ rowptr, const int* __restrict__ count,
    const float* __restrict__ bias, void* __restrict__ out_v, int n) {
  const int wave = threadIdx.x >> 6;
  const int lane = threadIdx.x & 63;
  const int half = lane >> 5;
  const int l = lane & 31;
  const int row = blockIdx.x * 4 + wave;
  if (row >= n) return;
  const int start = rowptr[row];
  const int len = count[row];
  const uint2* h2 = (const uint2*)h;  // src*32 + l

  float a0 = 0.f, a1 = 0.f, a2 = 0.f, a3 = 0.f;
  int j = 0;
  for (; j + 4 <= len; j += 4) {
    int2 e0 = sorted[start + j];
    int2 e1 = sorted[start + j + 1];
    int2 e2 = sorted[start + j + 2];
    int2 e3 = sorted[start + j + 3];
    int sA = half ? e1.x : e0.x;
    int sB = half ? e3.x : e2.x;
    float vA = __int_as_float(half ? e1.y : e0.y);
    float vB = __int_as_float(half ? e3.y : e2.y);
    uint2 uA = h2[(size_t)sA * 32 + l];
    uint2 uB = h2[(size_t)sB * 32 + l];
    a0 += vA * bf_lo(uA.x); a1 += vA * bf_hi(uA.x);
    a2 += vA * bf_lo(uA.y); a3 += vA * bf_hi(uA.y);
    a0 += vB * bf_lo(uB.x); a1 += vB * bf_hi(uB.x);
    a2 += vB * bf_lo(uB.y); a3 += vB * bf_hi(uB.y);
  }
  for (; j + 2 <= len; j += 2) {
    int2 e0 = sorted[start + j];
    int2 e1 = sorted[start + j + 1];
    int sA = half ? e1.x : e0.x;
    float vA = __int_as_float(half ? e1.y : e0.y);
    uint2 uA = h2[(size_t)sA * 32 + l];
    a0 += vA * bf_lo(uA.x); a1 += vA * bf_hi(uA.x);
    a2 += vA * bf_lo(uA.y); a3 += vA * bf_hi(uA.y);
  }
  if (j < len) {  // odd tail: half 1 contributes 0
    int2 e0 = sorted[start + j];
    float vA = half ? 0.0f : __int_as_float(e0.y);
    uint2 uA = h2[(size_t)e0.x * 32 + l];
    a0 += vA * bf_lo(uA.x); a1 += vA * bf_hi(uA.x);
    a2 += vA * bf_lo(uA.y); a3 += vA * bf_hi(uA.y);
  }

  // Merge the two halves' partial sums (lane l and lane l+32 hold same dims).
  a0 += __shfl_xor(a0, 32);
  a1 += __shfl_xor(a1, 32);
  a2 += __shfl_xor(a2, 32);
  a3 += __shfl_xor(a3, 32);

  float4 bb = ((const float4*)bias)[l];
  a0 += bb.x; a1 += bb.y; a2 += bb.z; a3 += bb.w;

  if (MODE == 0) {
    if (half == 0) {
      uint2 pk;
      pk.x = pack_bf16x2(1.0f / (1.0f + __expf(-a0)), 1.0f / (1.0f + __expf(-a1)));
      pk.y = pack_bf16x2(1.0f / (1.0f + __expf(-a2)), 1.0f / (1.0f + __expf(-a3)));
      ((uint2*)out_v)[(size_t)row * 32 + l] = pk;
    }
  } else {
    float m = fmaxf(fmaxf(a0, a1), fmaxf(a2, a3));
#pragma unroll
    for (int off = 16; off; off >>= 1) m = fmaxf(m, __shfl_xor(m, off));
    float e0 = __expf(a0 - m), e1 = __expf(a1 - m);
    float e2 = __expf(a2 - m), e3 = __expf(a3 - m);
    float s = (e0 + e1) + (e2 + e3);
#pragma unroll
    for (int off = 16; off; off >>= 1) s += __shfl_xor(s, off);
    float inv = 1.0f / s;
    if (half == 0) {
      ((float4*)out_v)[(size_t)row * 32 + l] =
          make_float4(e0 * inv, e1 * inv, e2 * inv, e3 * inv);
    }
  }
}

// ---------------------------------------------------------------------------
extern "C" void kernel_launch(void* const* d_in, const int* in_sizes, int n_in,
                              void* d_out, int out_size, void* d_ws, size_t ws_size,
                              hipStream_t stream) {
  const float* x  = (const float*)d_in[0];
  const float* ev = (const float*)d_in[1];
  const float* W1 = (const float*)d_in[2];
  const float* b1 = (const float*)d_in[3];
  const float* W2 = (const float*)d_in[4];
  const float* b2 = (const float*)d_in[5];
  const float* W3 = (const float*)d_in[6];
  const float* b3 = (const float*)d_in[7];
  const int* es = (const int*)d_in[8];
  const int* ed = (const int*)d_in[9];

  const int N = in_sizes[0] / D;
  const int E = in_sizes[1];

  // Workspace layout (all 16B-aligned)
  char* p = (char*)d_ws;
  unsigned int* BA = (unsigned int*)p; p += (size_t)N * 64 * sizeof(unsigned int);
  unsigned int* BB = (unsigned int*)p; p += (size_t)N * 64 * sizeof(unsigned int);
  int2* sorted = (int2*)p;          p += (size_t)E * sizeof(int2);
  unsigned short* Wb = (unsigned short*)p; p += 3 * (size_t)D * D * sizeof(unsigned short);
  int* count  = (int*)p;            p += (size_t)N * sizeof(int);
  int* rowptr = (int*)p;            p += (size_t)N * sizeof(int);
  int* cursor = (int*)p;            p += (size_t)N * sizeof(int);
  int* blockSums = (int*)p;         p += 1024 * sizeof(int);

  const int eblk = (E + 255) / 256;
  const int nblk256 = (N + 255) / 256;
  const int nblkScan = (N + SCAN_CHUNK - 1) / SCAN_CHUNK;
  const int rowgrid = (N + 3) / 4;
  const int dense_grid = (N + 127) / 128;

  // --- Build dst-sorted CSR + bf16 weights ---
  (void)hipMemsetAsync(count, 0, (size_t)N * sizeof(int), stream);
  hist_kernel<<<eblk, 256, 0, stream>>>(ed, count, E);
  cast_w<<<dim3((D * D + 255) / 256, 3), 256, 0, stream>>>(W1, W2, W3, Wb);
  scan_blocks<<<nblkScan, 256, 0, stream>>>(count, rowptr, blockSums, N);
  scan_top<<<1, 256, 0, stream>>>(blockSums, nblkScan);
  add_offsets<<<nblk256, 256, 0, stream>>>(rowptr, cursor, blockSums, N);
  scatter_edges<<<eblk, 256, 0, stream>>>(es, ed, ev, cursor, sorted, E);

  // --- Layer 1: Y1 = x@W1^T (fp32 in), h1 = sigmoid(A@Y1 + b1) ---
  dense_nt<1><<<dense_grid, 256, 0, stream>>>(x, Wb + 0 * D * D,
                                              (unsigned short*)BA, N);
  spmm_fused<0><<<rowgrid, 256, 0, stream>>>(BA, sorted, rowptr, count, b1, BB, N);
  // --- Layer 2 ---
  dense_nt<0><<<dense_grid, 256, 0, stream>>>(BB, Wb + 1 * D * D,
                                              (unsigned short*)BA, N);
  spmm_fused<0><<<rowgrid, 256, 0, stream>>>(BA, sorted, rowptr, count, b2, BB, N);
  // --- Layer 3: Y3 = h2@W3^T, out = softmax(A@Y3 + b3) ---
  dense_nt<0><<<dense_grid, 256, 0, stream>>>(BB, Wb + 2 * D * D,
                                              (unsigned short*)BA, N);
  spmm_fused<1><<<rowgrid, 256, 0, stream>>>(BA, sorted, rowptr, count, b3, d_out, N);
}

// Round 7
// 342.866 us; speedup vs baseline: 1.1507x; 1.1507x over previous
//
#include <hip/hip_runtime.h>
#include <hip/hip_bf16.h>
#include <cstdint>
#include <cstddef>

#define D 128
#define SCAN_CHUNK 1024

typedef __attribute__((ext_vector_type(8))) __bf16 bf16v8;
typedef __attribute__((ext_vector_type(4))) float f32v4;

// Round-to-nearest-even fp32 -> bf16 (bits), packed pair.
__device__ inline unsigned int pack_bf16x2(float a, float b) {
  unsigned int ua = __float_as_uint(a);
  unsigned int ub = __float_as_uint(b);
  ua = (ua + 0x7fffu + ((ua >> 16) & 1u)) >> 16;
  ub = (ub + 0x7fffu + ((ub >> 16) & 1u)) >> 16;
  return ua | (ub << 16);
}
__device__ inline float bf_lo(unsigned int u) { return __uint_as_float(u << 16); }
__device__ inline float bf_hi(unsigned int u) { return __uint_as_float(u & 0xffff0000u); }

// ---------------------------------------------------------------------------
// Counting-sort pipeline: build dst-sorted CSR of (src, val) once per call.
// ---------------------------------------------------------------------------
__global__ __launch_bounds__(256) void hist_kernel(
    const int* __restrict__ dst, int* __restrict__ count, int E) {
  int e = blockIdx.x * 256 + threadIdx.x;
  if (e < E) atomicAdd(&count[dst[e]], 1);
}

__global__ __launch_bounds__(256) void scan_blocks(
    const int* __restrict__ count, int* __restrict__ rowptr,
    int* __restrict__ blockSums, int n) {
  __shared__ int sdata[256];
  const int tid = threadIdx.x;
  const int base = blockIdx.x * SCAN_CHUNK;
  int v[4];
#pragma unroll
  for (int k = 0; k < 4; ++k) {
    int idx = base + tid * 4 + k;
    v[k] = (idx < n) ? count[idx] : 0;
  }
  int s = v[0] + v[1] + v[2] + v[3];
  sdata[tid] = s;
  __syncthreads();
  for (int off = 1; off < 256; off <<= 1) {
    int x = (tid >= off) ? sdata[tid - off] : 0;
    __syncthreads();
    sdata[tid] += x;
    __syncthreads();
  }
  int run = sdata[tid] - s;
#pragma unroll
  for (int k = 0; k < 4; ++k) {
    int idx = base + tid * 4 + k;
    if (idx < n) rowptr[idx] = run;
    run += v[k];
  }
  if (tid == 255) blockSums[blockIdx.x] = sdata[255];
}

__global__ __launch_bounds__(256) void scan_top(int* __restrict__ bs, int nblk) {
  __shared__ int sdata[256];
  const int tid = threadIdx.x;
  int v[4];
#pragma unroll
  for (int k = 0; k < 4; ++k) {
    int idx = tid * 4 + k;
    v[k] = (idx < nblk) ? bs[idx] : 0;
  }
  int s = v[0] + v[1] + v[2] + v[3];
  sdata[tid] = s;
  __syncthreads();
  for (int off = 1; off < 256; off <<= 1) {
    int x = (tid >= off) ? sdata[tid - off] : 0;
    __syncthreads();
    sdata[tid] += x;
    __syncthreads();
  }
  int run = sdata[tid] - s;
#pragma unroll
  for (int k = 0; k < 4; ++k) {
    int idx = tid * 4 + k;
    if (idx < nblk) { int t = v[k]; bs[idx] = run; run += t; }
  }
}

__global__ __launch_bounds__(256) void add_offsets(
    int* __restrict__ rowptr, int* __restrict__ cursor,
    const int* __restrict__ bs, int n) {
  int i = blockIdx.x * 256 + threadIdx.x;
  if (i < n) {
    int v = rowptr[i] + bs[i >> 10];
    rowptr[i] = v;
    cursor[i] = v;
  }
}

__global__ __launch_bounds__(256) void scatter_edges(
    const int* __restrict__ src, const int* __restrict__ dst,
    const float* __restrict__ val, int* __restrict__ cursor,
    int2* __restrict__ sorted, int E) {
  int e = blockIdx.x * 256 + threadIdx.x;
  if (e < E) {
    int t = dst[e];
    int pos = atomicAdd(&cursor[t], 1);
    sorted[pos] = make_int2(src[e], __float_as_int(val[e]));
  }
}

// ---------------------------------------------------------------------------
// Weight cast: W (3 matrices, fp32 128x128) -> bf16, once per call.
// ---------------------------------------------------------------------------
__global__ __launch_bounds__(256) void cast_w(
    const float* __restrict__ W1, const float* __restrict__ W2,
    const float* __restrict__ W3, unsigned short* __restrict__ out) {
  const float* src[3] = {W1, W2, W3};
  int m = blockIdx.y;
  int i = blockIdx.x * 256 + threadIdx.x;
  if (i < D * D) {
    unsigned int u = __float_as_uint(src[m][i]);
    out[(size_t)m * D * D + i] =
        (unsigned short)((u + 0x7fffu + ((u >> 16) & 1u)) >> 16);
  }
}

// ---------------------------------------------------------------------------
// Dense transform Y = in @ W^T (bias/act fused into following SpMM).
// Round-5 form: BOTH H and W staged in LDS (W via strided-global reads in
// the MFMA loop regressed ~8us/dispatch in round 6 — gather-shaped B reads
// stall MFMA on vmcnt).
// ---------------------------------------------------------------------------
template <int F32IN>
__global__ __launch_bounds__(256) void dense_nt(
    const void* __restrict__ in_v, const unsigned short* __restrict__ Wb,
    unsigned short* __restrict__ out, int M) {
  __shared__ __align__(16) unsigned short Hs[128 * 136];
  __shared__ __align__(16) unsigned short Ws[128 * 136];

  const int tid = threadIdx.x;
  const int w = tid >> 6;
  const int lane = tid & 63;
  const int lane15 = lane & 15;
  const int quad = lane >> 4;
  const int row0 = blockIdx.x * 128;

  const uint4* w16 = (const uint4*)Wb;
#pragma unroll
  for (int it = 0; it < 8; ++it) {
    int c = it * 256 + tid;  // 0..2047
    int r = c >> 4;
    int ck = c & 15;
    *(uint4*)&Ws[r * 136 + ck * 8] = w16[(size_t)r * 16 + ck];
  }

  if (F32IN) {
    const float4* in32 = (const float4*)in_v;  // 32 chunks of 4 floats per row
#pragma unroll
    for (int it = 0; it < 16; ++it) {
      int c = it * 256 + tid;  // 0..4095
      int r = c >> 5;
      int ck = c & 31;
      float4 g = make_float4(0.f, 0.f, 0.f, 0.f);
      if (row0 + r < M) g = in32[(size_t)(row0 + r) * 32 + ck];
      uint2 pk = make_uint2(pack_bf16x2(g.x, g.y), pack_bf16x2(g.z, g.w));
      *(uint2*)&Hs[r * 136 + ck * 4] = pk;
    }
  } else {
    const uint4* in16 = (const uint4*)in_v;  // 16 chunks per bf16 row
#pragma unroll
    for (int it = 0; it < 8; ++it) {
      int c = it * 256 + tid;
      int r = c >> 4;
      int ck = c & 15;
      uint4 g = make_uint4(0, 0, 0, 0);
      if (row0 + r < M) g = in16[(size_t)(row0 + r) * 16 + ck];
      *(uint4*)&Hs[r * 136 + ck * 8] = g;
    }
  }
  __syncthreads();

  f32v4 acc[2][8];
#pragma unroll
  for (int mt = 0; mt < 2; ++mt)
#pragma unroll
    for (int nt = 0; nt < 8; ++nt) acc[mt][nt] = (f32v4){0.f, 0.f, 0.f, 0.f};

#pragma unroll
  for (int kt = 0; kt < 4; ++kt) {
    const int ko = kt * 32 + quad * 8;
    bf16v8 a0 = *(const bf16v8*)&Hs[(w * 32 + lane15) * 136 + ko];
    bf16v8 a1 = *(const bf16v8*)&Hs[(w * 32 + 16 + lane15) * 136 + ko];
#pragma unroll
    for (int nt = 0; nt < 8; ++nt) {
      bf16v8 b = *(const bf16v8*)&Ws[(nt * 16 + lane15) * 136 + ko];
      acc[0][nt] = __builtin_amdgcn_mfma_f32_16x16x32_bf16(a0, b, acc[0][nt], 0, 0, 0);
      acc[1][nt] = __builtin_amdgcn_mfma_f32_16x16x32_bf16(a1, b, acc[1][nt], 0, 0, 0);
    }
  }

#pragma unroll
  for (int mt = 0; mt < 2; ++mt) {
#pragma unroll
    for (int r = 0; r < 4; ++r) {
      int grow = row0 + w * 32 + mt * 16 + quad * 4 + r;
      if (grow < M) {
#pragma unroll
        for (int nt = 0; nt < 8; ++nt) {
          unsigned int u = __float_as_uint(acc[mt][nt][r]);
          out[(size_t)grow * D + nt * 16 + lane15] =
              (unsigned short)((u + 0x7fffu + ((u >> 16) & 1u)) >> 16);
        }
      }
    }
  }
}

// ---------------------------------------------------------------------------
// Fused SpMM, latency-optimized. One wave per row (row made wave-uniform via
// readfirstlane so rowptr/count/edge-records compile to scalar loads).
// First 8 edges straight-line: 8 record s_loads + 4 pair-gathers all in
// flight concurrently; lanes past the row's length clamp to the row's last
// edge (gather lands on already-fetched lines) with val=0. Uniform scalar
// loop handles len>8 (~20% of rows, Poisson lambda=6.4).
// Halves: half h gathers edge k+h of each pair via uint2 (8B/lane x 32 lanes
// = full 256B row); lane l owns dims 4l..4l+3; shfl_xor(32) merges halves.
// MODE 0: bias+sigmoid -> bf16.  MODE 1: bias+row-softmax -> fp32.
// ---------------------------------------------------------------------------
template <int MODE>
__global__ __launch_bounds__(256) void spmm_fused(
    const unsigned int* __restrict__ h, const int2* __restrict__ sorted,
    const int* __restrict__ rowptr, const int* __restrict__ count,
    const float* __restrict__ bias, void* __restrict__ out_v, int n, int E) {
  const int wave = threadIdx.x >> 6;
  const int lane = threadIdx.x & 63;
  const int half = lane >> 5;
  const int l = lane & 31;
  int row = blockIdx.x * 4 + wave;
  row = __builtin_amdgcn_readfirstlane(row);
  if (row >= n) return;
  const int start = rowptr[row];
  const int len = count[row];
  const int lm1 = (len > 0) ? (len - 1) : 0;
  const int Em1 = E - 1;
  const uint2* h2 = (const uint2*)h;

  float4 bb = ((const float4*)bias)[l];  // hoisted: overlaps with gathers

  float a0 = 0.f, a1 = 0.f, a2 = 0.f, a3 = 0.f;

  // --- straight-line first 8 edges ---
#pragma unroll
  for (int k = 0; k < 8; k += 2) {
    int i0 = (k < lm1) ? k : lm1;
    int i1 = (k + 1 < lm1) ? (k + 1) : lm1;
    int e0 = start + i0; if (e0 > Em1) e0 = Em1;
    int e1 = start + i1; if (e1 > Em1) e1 = Em1;
    int2 r0 = sorted[e0];
    int2 r1 = sorted[e1];
    int s = half ? r1.x : r0.x;
    float v = __int_as_float(half ? r1.y : r0.y);
    if (k + half >= len) v = 0.f;
    uint2 u = h2[(size_t)s * 32 + l];
    a0 += v * bf_lo(u.x); a1 += v * bf_hi(u.x);
    a2 += v * bf_lo(u.y); a3 += v * bf_hi(u.y);
  }

  // --- uniform remainder (len > 8) ---
  for (int j = 8; j < len; ++j) {
    int2 r = sorted[start + j];
    float v = (half == 0) ? __int_as_float(r.y) : 0.f;
    uint2 u = h2[(size_t)r.x * 32 + l];
    a0 += v * bf_lo(u.x); a1 += v * bf_hi(u.x);
    a2 += v * bf_lo(u.y); a3 += v * bf_hi(u.y);
  }

  // Merge the two halves' partial sums.
  a0 += __shfl_xor(a0, 32);
  a1 += __shfl_xor(a1, 32);
  a2 += __shfl_xor(a2, 32);
  a3 += __shfl_xor(a3, 32);

  a0 += bb.x; a1 += bb.y; a2 += bb.z; a3 += bb.w;

  if (MODE == 0) {
    if (half == 0) {
      uint2 pk;
      pk.x = pack_bf16x2(1.0f / (1.0f + __expf(-a0)), 1.0f / (1.0f + __expf(-a1)));
      pk.y = pack_bf16x2(1.0f / (1.0f + __expf(-a2)), 1.0f / (1.0f + __expf(-a3)));
      ((uint2*)out_v)[(size_t)row * 32 + l] = pk;
    }
  } else {
    float m = fmaxf(fmaxf(a0, a1), fmaxf(a2, a3));
#pragma unroll
    for (int off = 16; off; off >>= 1) m = fmaxf(m, __shfl_xor(m, off));
    float e0 = __expf(a0 - m), e1 = __expf(a1 - m);
    float e2 = __expf(a2 - m), e3 = __expf(a3 - m);
    float s = (e0 + e1) + (e2 + e3);
#pragma unroll
    for (int off = 16; off; off >>= 1) s += __shfl_xor(s, off);
    float inv = 1.0f / s;
    if (half == 0) {
      ((float4*)out_v)[(size_t)row * 32 + l] =
          make_float4(e0 * inv, e1 * inv, e2 * inv, e3 * inv);
    }
  }
}

// ---------------------------------------------------------------------------
extern "C" void kernel_launch(void* const* d_in, const int* in_sizes, int n_in,
                              void* d_out, int out_size, void* d_ws, size_t ws_size,
                              hipStream_t stream) {
  const float* x  = (const float*)d_in[0];
  const float* ev = (const float*)d_in[1];
  const float* W1 = (const float*)d_in[2];
  const float* b1 = (const float*)d_in[3];
  const float* W2 = (const float*)d_in[4];
  const float* b2 = (const float*)d_in[5];
  const float* W3 = (const float*)d_in[6];
  const float* b3 = (const float*)d_in[7];
  const int* es = (const int*)d_in[8];
  const int* ed = (const int*)d_in[9];

  const int N = in_sizes[0] / D;
  const int E = in_sizes[1];

  // Workspace layout (all 16B-aligned)
  char* p = (char*)d_ws;
  unsigned int* BA = (unsigned int*)p; p += (size_t)N * 64 * sizeof(unsigned int);
  unsigned int* BB = (unsigned int*)p; p += (size_t)N * 64 * sizeof(unsigned int);
  int2* sorted = (int2*)p;          p += (size_t)E * sizeof(int2);
  unsigned short* Wb = (unsigned short*)p; p += 3 * (size_t)D * D * sizeof(unsigned short);
  int* count  = (int*)p;            p += (size_t)N * sizeof(int);
  int* rowptr = (int*)p;            p += (size_t)N * sizeof(int);
  int* cursor = (int*)p;            p += (size_t)N * sizeof(int);
  int* blockSums = (int*)p;         p += 1024 * sizeof(int);

  const int eblk = (E + 255) / 256;
  const int nblk256 = (N + 255) / 256;
  const int nblkScan = (N + SCAN_CHUNK - 1) / SCAN_CHUNK;
  const int rowgrid = (N + 3) / 4;
  const int dense_grid = (N + 127) / 128;

  // --- Build dst-sorted CSR + bf16 weights ---
  (void)hipMemsetAsync(count, 0, (size_t)N * sizeof(int), stream);
  hist_kernel<<<eblk, 256, 0, stream>>>(ed, count, E);
  cast_w<<<dim3((D * D + 255) / 256, 3), 256, 0, stream>>>(W1, W2, W3, Wb);
  scan_blocks<<<nblkScan, 256, 0, stream>>>(count, rowptr, blockSums, N);
  scan_top<<<1, 256, 0, stream>>>(blockSums, nblkScan);
  add_offsets<<<nblk256, 256, 0, stream>>>(rowptr, cursor, blockSums, N);
  scatter_edges<<<eblk, 256, 0, stream>>>(es, ed, ev, cursor, sorted, E);

  // --- Layer 1: Y1 = x@W1^T (fp32 in), h1 = sigmoid(A@Y1 + b1) ---
  dense_nt<1><<<dense_grid, 256, 0, stream>>>(x, Wb + 0 * D * D,
                                              (unsigned short*)BA, N);
  spmm_fused<0><<<rowgrid, 256, 0, stream>>>(BA, sorted, rowptr, count, b1, BB, N, E);
  // --- Layer 2 ---
  dense_nt<0><<<dense_grid, 256, 0, stream>>>(BB, Wb + 1 * D * D,
                                              (unsigned short*)BA, N);
  spmm_fused<0><<<rowgrid, 256, 0, stream>>>(BA, sorted, rowptr, count, b2, BB, N, E);
  // --- Layer 3: Y3 = h2@W3^T, out = softmax(A@Y3 + b3) ---
  dense_nt<0><<<dense_grid, 256, 0, stream>>>(BB, Wb + 2 * D * D,
                                              (unsigned short*)BA, N);
  spmm_fused<1><<<rowgrid, 256, 0, stream>>>(BA, sorted, rowptr, count, b3, d_out, N, E);
}